// Round 1
// baseline (770.261 us; speedup 1.0000x reference)
//
#include <hip/hip_runtime.h>
#include <math.h>

// GCN: out = softmax( S·relu((S·h)W1 + b1) · W2 + b2 ),  S = in-edge sum + self-loop.
// Uses (S·x)·W2 == S·(x·W2) to scatter 40 floats/edge in layer 2 instead of 128.

constexpr int N = 100000;
constexpr int E = 1200000;
constexpr int D = 64;    // input dim
constexpr int H = 128;   // hidden
constexpr int C = 40;    // classes

// ---- layer-1 aggregation: agg1[dst*D+f] += h[src*D+f], one thread per (edge,feat)
__global__ __launch_bounds__(256) void scatter_d64(const float* __restrict__ h,
                                                   const int* __restrict__ adj,
                                                   float* __restrict__ agg) {
    int t = blockIdx.x * blockDim.x + threadIdx.x;   // E*D = 76.8M < 2^31
    if (t >= E * D) return;
    int e = t >> 6;          // /64
    int f = t & 63;
    int src = adj[2 * e];
    int dst = adj[2 * e + 1];
    atomicAdd(&agg[dst * D + f], h[src * D + f]);
}

// ---- X = relu(agg1 @ W1 + b1); 2 rows per 256-thread block, A-rows in LDS
__global__ __launch_bounds__(256) void gemm1_relu(const float* __restrict__ A,
                                                  const float* __restrict__ W1,
                                                  const float* __restrict__ b1,
                                                  float* __restrict__ X) {
    __shared__ float a_s[2][D];
    int row0 = blockIdx.x * 2;
    if (threadIdx.x < 2 * D) {
        int r = threadIdx.x >> 6, k = threadIdx.x & 63;
        a_s[r][k] = A[(row0 + r) * D + k];
    }
    __syncthreads();
    int lrow = threadIdx.x >> 7;       // 0..1
    int col  = threadIdx.x & 127;      // 0..127
    int row  = row0 + lrow;
    float acc = b1[col];
#pragma unroll
    for (int k = 0; k < D; ++k)
        acc = fmaf(a_s[lrow][k], W1[k * H + col], acc);
    X[row * H + col] = fmaxf(acc, 0.f);
}

// ---- Z = X @ W2 (no bias yet); AZ = Z (self-loop init). One wave per row, W2 in LDS.
__global__ __launch_bounds__(256) void gemm2(const float* __restrict__ X,
                                             const float* __restrict__ W2,
                                             float* __restrict__ Z,
                                             float* __restrict__ AZ) {
    __shared__ float w_s[H * C];   // 128*40*4 = 20 KB
    for (int i = threadIdx.x; i < H * C; i += 256) w_s[i] = W2[i];
    __syncthreads();
    int row  = blockIdx.x * 4 + (threadIdx.x >> 6);
    int lane = threadIdx.x & 63;
    const float* a = X + row * H;
    if (lane < C) {
        float acc = 0.f;
#pragma unroll 8
        for (int k = 0; k < H; ++k)
            acc = fmaf(a[k], w_s[k * C + lane], acc);   // a[k] broadcast across lanes
        Z[row * C + lane]  = acc;
        AZ[row * C + lane] = acc;
    }
}

// ---- layer-2 aggregation in class space: AZ[dst*C+c] += Z[src*C+c]
__global__ __launch_bounds__(256) void scatter_c40(const float* __restrict__ Z,
                                                   const int* __restrict__ adj,
                                                   float* __restrict__ AZ) {
    int t = blockIdx.x * blockDim.x + threadIdx.x;   // E*C = 48M < 2^31
    if (t >= E * C) return;
    int e = t / C;
    int c = t - e * C;
    int src = adj[2 * e];
    int dst = adj[2 * e + 1];
    atomicAdd(&AZ[dst * C + c], Z[src * C + c]);
}

// ---- out = softmax(AZ + b2) per row; one wave per row, 64-lane butterfly reduce
__global__ __launch_bounds__(256) void bias_softmax(const float* __restrict__ AZ,
                                                    const float* __restrict__ b2,
                                                    float* __restrict__ out) {
    int row  = blockIdx.x * 4 + (threadIdx.x >> 6);
    int lane = threadIdx.x & 63;
    float acc = (lane < C) ? (AZ[row * C + lane] + b2[lane]) : -INFINITY;
    float m = acc;
    for (int off = 32; off; off >>= 1) m = fmaxf(m, __shfl_xor(m, off));
    float ex = (lane < C) ? expf(acc - m) : 0.f;
    float s = ex;
    for (int off = 32; off; off >>= 1) s += __shfl_xor(s, off);
    if (lane < C) out[row * C + lane] = ex / s;
}

extern "C" void kernel_launch(void* const* d_in, const int* in_sizes, int n_in,
                              void* d_out, int out_size, void* d_ws, size_t ws_size,
                              hipStream_t stream) {
    const float* h   = (const float*)d_in[0];   // N*D
    const int*   adj = (const int*)  d_in[1];   // E*2
    const float* W1  = (const float*)d_in[2];   // D*H
    const float* b1  = (const float*)d_in[3];   // H
    const float* W2  = (const float*)d_in[4];   // H*C
    const float* b2  = (const float*)d_in[5];   // C
    float* out = (float*)d_out;                 // N*C fp32

    // workspace layout (fp32): agg1[N*D] | X[N*H] | Z[N*C] | AZ[N*C]  = 108.8 MB
    float* agg1 = (float*)d_ws;
    float* X    = agg1 + (size_t)N * D;
    float* Z    = X    + (size_t)N * H;
    float* AZ   = Z    + (size_t)N * C;

    // self-loops for layer 1: agg1 starts as h
    hipMemcpyAsync(agg1, h, (size_t)N * D * sizeof(float),
                   hipMemcpyDeviceToDevice, stream);
    scatter_d64<<<(E * D + 255) / 256, 256, 0, stream>>>(h, adj, agg1);
    gemm1_relu<<<N / 2, 256, 0, stream>>>(agg1, W1, b1, X);
    gemm2<<<N / 4, 256, 0, stream>>>(X, W2, Z, AZ);          // AZ init = self-loop
    scatter_c40<<<(E * C + 255) / 256, 256, 0, stream>>>(Z, adj, AZ);
    bias_softmax<<<N / 4, 256, 0, stream>>>(AZ, b2, out);
}

// Round 2
// 539.854 us; speedup vs baseline: 1.4268x; 1.4268x over previous
//
#include <hip/hip_runtime.h>
#include <math.h>

// GCN: out = softmax( S·relu((S·h)W1 + b1) · W2 + b2 ),  S = in-edge sum + self-loop.
// Round 2: scatters (fp32 atomic write-through, 420us) replaced by CSR build + gather.
// (S·x)·W2 == S·(x·W2): layer-2 aggregation done in class space (40 floats/edge).

constexpr int N = 100000;
constexpr int E = 1200000;
constexpr int D = 64;    // input dim
constexpr int H = 128;   // hidden
constexpr int C = 40;    // classes
constexpr int NB_SCAN = (N + 255) / 256;   // 391 scan blocks

// ---------------- CSR build ----------------
__global__ __launch_bounds__(256) void histo(const int* __restrict__ adj,
                                             int* __restrict__ deg) {
    int e = blockIdx.x * 256 + threadIdx.x;
    if (e < E) atomicAdd(&deg[adj[2 * e + 1]], 1);
}

// per-block inclusive scan of deg -> row_start (temp), block sums -> bsum
__global__ __launch_bounds__(256) void scan1(const int* __restrict__ deg,
                                             int* __restrict__ incl,
                                             int* __restrict__ bsum) {
    __shared__ int s[256];
    int i = blockIdx.x * 256 + threadIdx.x;
    int v = (i < N) ? deg[i] : 0;
    s[threadIdx.x] = v;
    __syncthreads();
    for (int off = 1; off < 256; off <<= 1) {
        int x = (threadIdx.x >= (unsigned)off) ? s[threadIdx.x - off] : 0;
        __syncthreads();
        s[threadIdx.x] += x;
        __syncthreads();
    }
    if (i < N) incl[i] = s[threadIdx.x];
    if (threadIdx.x == 255) bsum[blockIdx.x] = s[255];
}

// exclusive scan of the 391 block sums, single block of 512
__global__ __launch_bounds__(512) void scan2(int* __restrict__ bsum) {
    __shared__ int s[512];
    int t = threadIdx.x;
    int v = (t < NB_SCAN) ? bsum[t] : 0;
    s[t] = v;
    __syncthreads();
    for (int off = 1; off < 512; off <<= 1) {
        int x = (t >= off) ? s[t - off] : 0;
        __syncthreads();
        s[t] += x;
        __syncthreads();
    }
    if (t < NB_SCAN) bsum[t] = s[t] - v;   // exclusive
}

// row_start[i] = incl[i] - deg[i] + bsum_excl[block]  (in-place), cursor = row_start
__global__ __launch_bounds__(256) void scan3(int* __restrict__ row_start,   // holds incl
                                             const int* __restrict__ deg,
                                             const int* __restrict__ bsum,
                                             int* __restrict__ cursor) {
    int i = blockIdx.x * 256 + threadIdx.x;
    if (i < N) {
        int rs = row_start[i] - deg[i] + bsum[blockIdx.x];
        row_start[i] = rs;
        cursor[i]    = rs;
    }
}

__global__ __launch_bounds__(256) void fill_csr(const int* __restrict__ adj,
                                                int* __restrict__ cursor,
                                                int* __restrict__ csr) {
    int e = blockIdx.x * 256 + threadIdx.x;
    if (e < E) {
        int src = adj[2 * e];
        int dst = adj[2 * e + 1];
        int p = atomicAdd(&cursor[dst], 1);
        csr[p] = src;
    }
}

// ---------------- layer-1 gather: agg[node] = h[node] + sum_{in-edges} h[src] ----------
__global__ __launch_bounds__(256) void gather1(const float* __restrict__ h,
                                               const int* __restrict__ csr,
                                               const int* __restrict__ row_start,
                                               const int* __restrict__ deg,
                                               float* __restrict__ agg) {
    int node = blockIdx.x * 4 + (threadIdx.x >> 6);
    int lane = threadIdx.x & 63;
    float acc = h[node * D + lane];            // self-loop
    int rs = row_start[node], d = deg[node];
    int j = 0;
    for (; j + 4 <= d; j += 4) {               // ILP: batch 4 index loads, 4 row loads
        int s0 = csr[rs + j], s1 = csr[rs + j + 1];
        int s2 = csr[rs + j + 2], s3 = csr[rs + j + 3];
        acc += h[s0 * D + lane];
        acc += h[s1 * D + lane];
        acc += h[s2 * D + lane];
        acc += h[s3 * D + lane];
    }
    for (; j < d; ++j) acc += h[csr[rs + j] * D + lane];
    agg[node * D + lane] = acc;
}

// ---------------- X = relu(agg @ W1 + b1) ----------------
__global__ __launch_bounds__(256) void gemm1_relu(const float* __restrict__ A,
                                                  const float* __restrict__ W1,
                                                  const float* __restrict__ b1,
                                                  float* __restrict__ X) {
    __shared__ float a_s[2][D];
    int row0 = blockIdx.x * 2;
    if (threadIdx.x < 2 * D) {
        int r = threadIdx.x >> 6, k = threadIdx.x & 63;
        a_s[r][k] = A[(row0 + r) * D + k];
    }
    __syncthreads();
    int lrow = threadIdx.x >> 7;
    int col  = threadIdx.x & 127;
    float acc = b1[col];
#pragma unroll
    for (int k = 0; k < D; ++k)
        acc = fmaf(a_s[lrow][k], W1[k * H + col], acc);
    X[(row0 + lrow) * H + col] = fmaxf(acc, 0.f);
}

// ---------------- Z = X @ W2 ----------------
__global__ __launch_bounds__(256) void gemm2(const float* __restrict__ X,
                                             const float* __restrict__ W2,
                                             float* __restrict__ Z) {
    __shared__ float w_s[H * C];   // 20 KB
    for (int i = threadIdx.x; i < H * C; i += 256) w_s[i] = W2[i];
    __syncthreads();
    int row  = blockIdx.x * 4 + (threadIdx.x >> 6);
    int lane = threadIdx.x & 63;
    const float* a = X + row * H;
    if (lane < C) {
        float acc = 0.f;
#pragma unroll 8
        for (int k = 0; k < H; ++k)
            acc = fmaf(a[k], w_s[k * C + lane], acc);
        Z[row * C + lane] = acc;
    }
}

// ---------------- out[node] = softmax(Z[node] + sum Z[src] + b2) ----------------
__global__ __launch_bounds__(256) void gather2_softmax(const float* __restrict__ Z,
                                                       const int* __restrict__ csr,
                                                       const int* __restrict__ row_start,
                                                       const int* __restrict__ deg,
                                                       const float* __restrict__ b2,
                                                       float* __restrict__ out) {
    int node = blockIdx.x * 4 + (threadIdx.x >> 6);
    int lane = threadIdx.x & 63;
    int rs = row_start[node], d = deg[node];
    float acc = (lane < C) ? Z[node * C + lane] : 0.f;   // self-loop
    int j = 0;
    for (; j + 4 <= d; j += 4) {
        int s0 = csr[rs + j], s1 = csr[rs + j + 1];
        int s2 = csr[rs + j + 2], s3 = csr[rs + j + 3];
        if (lane < C) {
            acc += Z[s0 * C + lane];
            acc += Z[s1 * C + lane];
            acc += Z[s2 * C + lane];
            acc += Z[s3 * C + lane];
        }
    }
    for (; j < d; ++j) {
        int s = csr[rs + j];
        if (lane < C) acc += Z[s * C + lane];
    }
    float v = (lane < C) ? acc + b2[lane] : -INFINITY;
    float m = v;
    for (int off = 32; off; off >>= 1) m = fmaxf(m, __shfl_xor(m, off));
    float ex = (lane < C) ? expf(v - m) : 0.f;
    float ssum = ex;
    for (int off = 32; off; off >>= 1) ssum += __shfl_xor(ssum, off);
    if (lane < C) out[node * C + lane] = ex / ssum;
}

extern "C" void kernel_launch(void* const* d_in, const int* in_sizes, int n_in,
                              void* d_out, int out_size, void* d_ws, size_t ws_size,
                              hipStream_t stream) {
    const float* h   = (const float*)d_in[0];   // N*D
    const int*   adj = (const int*)  d_in[1];   // E*2
    const float* W1  = (const float*)d_in[2];   // D*H
    const float* b1  = (const float*)d_in[3];   // H
    const float* W2  = (const float*)d_in[4];   // H*C
    const float* b2  = (const float*)d_in[5];   // C
    float* out = (float*)d_out;                 // N*C fp32

    // workspace: agg1[N*D] X[N*H] Z[N*C] | deg[N] row_start[N] cursor[N] bsum[512] csr[E]
    float* agg1      = (float*)d_ws;
    float* X         = agg1 + (size_t)N * D;
    float* Z         = X    + (size_t)N * H;
    int*   deg       = (int*)(Z + (size_t)N * C);
    int*   row_start = deg + N;
    int*   cursor    = row_start + N;
    int*   bsum      = cursor + N;
    int*   csr       = bsum + 512;

    hipMemsetAsync(deg, 0, N * sizeof(int), stream);
    histo   <<<(E + 255) / 256, 256, 0, stream>>>(adj, deg);
    scan1   <<<NB_SCAN, 256, 0, stream>>>(deg, row_start, bsum);
    scan2   <<<1, 512, 0, stream>>>(bsum);
    scan3   <<<NB_SCAN, 256, 0, stream>>>(row_start, deg, bsum, cursor);
    fill_csr<<<(E + 255) / 256, 256, 0, stream>>>(adj, cursor, csr);

    gather1        <<<N / 4, 256, 0, stream>>>(h, csr, row_start, deg, agg1);
    gemm1_relu     <<<N / 2, 256, 0, stream>>>(agg1, W1, b1, X);
    gemm2          <<<N / 4, 256, 0, stream>>>(X, W2, Z);
    gather2_softmax<<<N / 4, 256, 0, stream>>>(Z, csr, row_start, deg, b2, out);
}

// Round 3
// 401.005 us; speedup vs baseline: 1.9208x; 1.3463x over previous
//
#include <hip/hip_runtime.h>
#include <math.h>

// GCN: out = softmax( S·relu((S·h)W1 + b1) · W2 + b2 ),  S = in-edge sum + self-loop.
// Round 3: both GEMMs rewritten as register-blocked LDS-tiled kernels
// (old versions did one scalar global load + one scalar LDS read per FMA).

constexpr int N = 100000;
constexpr int E = 1200000;
constexpr int D = 64;    // input dim
constexpr int H = 128;   // hidden
constexpr int C = 40;    // classes
constexpr int NB_SCAN = (N + 255) / 256;   // 391 scan blocks

// ---------------- CSR build ----------------
__global__ __launch_bounds__(256) void histo(const int* __restrict__ adj,
                                             int* __restrict__ deg) {
    int e = blockIdx.x * 256 + threadIdx.x;
    if (e < E) atomicAdd(&deg[adj[2 * e + 1]], 1);
}

__global__ __launch_bounds__(256) void scan1(const int* __restrict__ deg,
                                             int* __restrict__ incl,
                                             int* __restrict__ bsum) {
    __shared__ int s[256];
    int i = blockIdx.x * 256 + threadIdx.x;
    int v = (i < N) ? deg[i] : 0;
    s[threadIdx.x] = v;
    __syncthreads();
    for (int off = 1; off < 256; off <<= 1) {
        int x = (threadIdx.x >= (unsigned)off) ? s[threadIdx.x - off] : 0;
        __syncthreads();
        s[threadIdx.x] += x;
        __syncthreads();
    }
    if (i < N) incl[i] = s[threadIdx.x];
    if (threadIdx.x == 255) bsum[blockIdx.x] = s[255];
}

__global__ __launch_bounds__(512) void scan2(int* __restrict__ bsum) {
    __shared__ int s[512];
    int t = threadIdx.x;
    int v = (t < NB_SCAN) ? bsum[t] : 0;
    s[t] = v;
    __syncthreads();
    for (int off = 1; off < 512; off <<= 1) {
        int x = (t >= off) ? s[t - off] : 0;
        __syncthreads();
        s[t] += x;
        __syncthreads();
    }
    if (t < NB_SCAN) bsum[t] = s[t] - v;   // exclusive
}

__global__ __launch_bounds__(256) void scan3(int* __restrict__ row_start,   // holds incl
                                             const int* __restrict__ deg,
                                             const int* __restrict__ bsum,
                                             int* __restrict__ cursor) {
    int i = blockIdx.x * 256 + threadIdx.x;
    if (i < N) {
        int rs = row_start[i] - deg[i] + bsum[blockIdx.x];
        row_start[i] = rs;
        cursor[i]    = rs;
    }
}

__global__ __launch_bounds__(256) void fill_csr(const int* __restrict__ adj,
                                                int* __restrict__ cursor,
                                                int* __restrict__ csr) {
    int e = blockIdx.x * 256 + threadIdx.x;
    if (e < E) {
        int src = adj[2 * e];
        int dst = adj[2 * e + 1];
        int p = atomicAdd(&cursor[dst], 1);
        csr[p] = src;
    }
}

// ---------------- layer-1 gather: agg[node] = h[node] + sum_{in-edges} h[src] ----------
__global__ __launch_bounds__(256) void gather1(const float* __restrict__ h,
                                               const int* __restrict__ csr,
                                               const int* __restrict__ row_start,
                                               const int* __restrict__ deg,
                                               float* __restrict__ agg) {
    int node = blockIdx.x * 4 + (threadIdx.x >> 6);
    int lane = threadIdx.x & 63;
    float acc = h[node * D + lane];            // self-loop
    int rs = row_start[node], d = deg[node];
    int j = 0;
    for (; j + 4 <= d; j += 4) {
        int s0 = csr[rs + j], s1 = csr[rs + j + 1];
        int s2 = csr[rs + j + 2], s3 = csr[rs + j + 3];
        acc += h[s0 * D + lane];
        acc += h[s1 * D + lane];
        acc += h[s2 * D + lane];
        acc += h[s3 * D + lane];
    }
    for (; j < d; ++j) acc += h[csr[rs + j] * D + lane];
    agg[node * D + lane] = acc;
}

// ---------------- X = relu(agg @ W1 + b1), tiled ----------------
// tile: 16 rows x 128 cols, K=64. W1 (32KB) + A-tile (4KB) in LDS.
// threads: 64 thread-cols (lane) x 4 thread-rows (tr); each thread: rows {tr+4i}, cols {lane, lane+64}.
__global__ __launch_bounds__(256) void gemm1_relu(const float* __restrict__ A,
                                                  const float* __restrict__ W1,
                                                  const float* __restrict__ b1,
                                                  float* __restrict__ X) {
    __shared__ float w_s[D * H];      // 32 KB, [k][col]
    __shared__ float a_s[16 * D];     // 4 KB,  [row][k]
    int row0 = blockIdx.x * 16;

    // stage W1: 8192 floats = 2048 float4, 8 per thread
    {
        const float4* src = (const float4*)W1;
        float4* dst = (float4*)w_s;
#pragma unroll
        for (int i = 0; i < 8; ++i)
            dst[threadIdx.x + i * 256] = src[threadIdx.x + i * 256];
    }
    // stage A tile: 1024 floats = 256 float4, 1 per thread
    {
        int r = threadIdx.x >> 4;          // 0..15
        int q = threadIdx.x & 15;          // 0..15 (float4 within row)
        float4 v = *(const float4*)&A[(row0 + r) * D + q * 4];
        *(float4*)&a_s[r * D + q * 4] = v;
    }
    __syncthreads();

    int tr   = threadIdx.x >> 6;       // 0..3
    int lane = threadIdx.x & 63;       // col base
    float acc[4][2] = {};
#pragma unroll
    for (int k = 0; k < D; ++k) {
        float b0 = w_s[k * H + lane];
        float b1v = w_s[k * H + lane + 64];
#pragma unroll
        for (int i = 0; i < 4; ++i) {
            float a = a_s[(tr + 4 * i) * D + k];   // wave-broadcast
            acc[i][0] = fmaf(a, b0, acc[i][0]);
            acc[i][1] = fmaf(a, b1v, acc[i][1]);
        }
    }
    float bias0 = b1[lane], bias1 = b1[lane + 64];
#pragma unroll
    for (int i = 0; i < 4; ++i) {
        int row = row0 + tr + 4 * i;
        X[row * H + lane]      = fmaxf(acc[i][0] + bias0, 0.f);
        X[row * H + lane + 64] = fmaxf(acc[i][1] + bias1, 0.f);
    }
}

// ---------------- Z = X @ W2, tiled ----------------
// tile: 64 rows x 40 cols, K=128. W2 (20KB) + X-tile (64x132 padded, 33.8KB) in LDS.
// threads: tc = tid&7 (5 cols each), trow = tid>>3 (2 rows each). 10 acc/thread.
constexpr int XS = 132;   // padded X-tile row stride (2-way bank aliasing = free)
__global__ __launch_bounds__(256) void gemm2(const float* __restrict__ X,
                                             const float* __restrict__ W2,
                                             float* __restrict__ Z) {
    __shared__ float w_s[H * C];        // 20 KB, [k][c]
    __shared__ float x_s[64 * XS];      // 33.8 KB, [row][k]
    int row0 = blockIdx.x * 64;

    // stage W2: 5120 floats = 1280 float4, 5 per thread
    {
        const float4* src = (const float4*)W2;
        float4* dst = (float4*)w_s;
#pragma unroll
        for (int i = 0; i < 5; ++i)
            dst[threadIdx.x + i * 256] = src[threadIdx.x + i * 256];
    }
    // stage X tile: 64 rows x 128 = 2048 float4, 8 per thread (clamp row for tail block)
    {
#pragma unroll
        for (int i = 0; i < 8; ++i) {
            int idx = threadIdx.x + i * 256;
            int r = idx >> 5;              // 32 float4 per row
            int q = idx & 31;
            int grow = row0 + r;
            if (grow >= N) grow = N - 1;
            float4 v = *(const float4*)&X[grow * H + q * 4];
            *(float4*)&x_s[r * XS + q * 4] = v;
        }
    }
    __syncthreads();

    int tc   = threadIdx.x & 7;         // cols tc*5 .. tc*5+4
    int trow = threadIdx.x >> 3;        // rows trow*2, trow*2+1
    float acc[2][5] = {};
#pragma unroll 4
    for (int k = 0; k < H; ++k) {
        float b[5];
#pragma unroll
        for (int j = 0; j < 5; ++j) b[j] = w_s[k * C + tc * 5 + j];
        float a0 = x_s[(trow * 2) * XS + k];
        float a1 = x_s[(trow * 2 + 1) * XS + k];
#pragma unroll
        for (int j = 0; j < 5; ++j) {
            acc[0][j] = fmaf(a0, b[j], acc[0][j]);
            acc[1][j] = fmaf(a1, b[j], acc[1][j]);
        }
    }
#pragma unroll
    for (int i = 0; i < 2; ++i) {
        int row = row0 + trow * 2 + i;
        if (row < N) {
#pragma unroll
            for (int j = 0; j < 5; ++j)
                Z[row * C + tc * 5 + j] = acc[i][j];
        }
    }
}

// ---------------- out[node] = softmax(Z[node] + sum Z[src] + b2) ----------------
__global__ __launch_bounds__(256) void gather2_softmax(const float* __restrict__ Z,
                                                       const int* __restrict__ csr,
                                                       const int* __restrict__ row_start,
                                                       const int* __restrict__ deg,
                                                       const float* __restrict__ b2,
                                                       float* __restrict__ out) {
    int node = blockIdx.x * 4 + (threadIdx.x >> 6);
    int lane = threadIdx.x & 63;
    int rs = row_start[node], d = deg[node];
    float acc = (lane < C) ? Z[node * C + lane] : 0.f;   // self-loop
    int j = 0;
    for (; j + 4 <= d; j += 4) {
        int s0 = csr[rs + j], s1 = csr[rs + j + 1];
        int s2 = csr[rs + j + 2], s3 = csr[rs + j + 3];
        if (lane < C) {
            acc += Z[s0 * C + lane];
            acc += Z[s1 * C + lane];
            acc += Z[s2 * C + lane];
            acc += Z[s3 * C + lane];
        }
    }
    for (; j < d; ++j) {
        int s = csr[rs + j];
        if (lane < C) acc += Z[s * C + lane];
    }
    float v = (lane < C) ? acc + b2[lane] : -INFINITY;
    float m = v;
    for (int off = 32; off; off >>= 1) m = fmaxf(m, __shfl_xor(m, off));
    float ex = (lane < C) ? expf(v - m) : 0.f;
    float ssum = ex;
    for (int off = 32; off; off >>= 1) ssum += __shfl_xor(ssum, off);
    if (lane < C) out[node * C + lane] = ex / ssum;
}

extern "C" void kernel_launch(void* const* d_in, const int* in_sizes, int n_in,
                              void* d_out, int out_size, void* d_ws, size_t ws_size,
                              hipStream_t stream) {
    const float* h   = (const float*)d_in[0];   // N*D
    const int*   adj = (const int*)  d_in[1];   // E*2
    const float* W1  = (const float*)d_in[2];   // D*H
    const float* b1  = (const float*)d_in[3];   // H
    const float* W2  = (const float*)d_in[4];   // H*C
    const float* b2  = (const float*)d_in[5];   // C
    float* out = (float*)d_out;                 // N*C fp32

    // workspace: agg1[N*D] X[N*H] Z[N*C] | deg[N] row_start[N] cursor[N] bsum[512] csr[E]
    float* agg1      = (float*)d_ws;
    float* X         = agg1 + (size_t)N * D;
    float* Z         = X    + (size_t)N * H;
    int*   deg       = (int*)(Z + (size_t)N * C);
    int*   row_start = deg + N;
    int*   cursor    = row_start + N;
    int*   bsum      = cursor + N;
    int*   csr       = bsum + 512;

    hipMemsetAsync(deg, 0, N * sizeof(int), stream);
    histo   <<<(E + 255) / 256, 256, 0, stream>>>(adj, deg);
    scan1   <<<NB_SCAN, 256, 0, stream>>>(deg, row_start, bsum);
    scan2   <<<1, 512, 0, stream>>>(bsum);
    scan3   <<<NB_SCAN, 256, 0, stream>>>(row_start, deg, bsum, cursor);
    fill_csr<<<(E + 255) / 256, 256, 0, stream>>>(adj, cursor, csr);

    gather1        <<<N / 4, 256, 0, stream>>>(h, csr, row_start, deg, agg1);
    gemm1_relu     <<<N / 16, 256, 0, stream>>>(agg1, W1, b1, X);
    gemm2          <<<(N + 63) / 64, 256, 0, stream>>>(X, W2, Z);
    gather2_softmax<<<N / 4, 256, 0, stream>>>(Z, csr, row_start, deg, b2, out);
}